// Round 1
// baseline (545.005 us; speedup 1.0000x reference)
//
#include <hip/hip_runtime.h>

#define BM 64
#define BN 64
#define BK 32

// ---------------- CSR build ----------------
__global__ void hist_kernel(const int* __restrict__ dst, int* __restrict__ deg, int E) {
    int e = blockIdx.x * blockDim.x + threadIdx.x;
    if (e < E) atomicAdd(&deg[dst[e]], 1);
}

__global__ void scan_kernel(const int* __restrict__ deg, int* __restrict__ row_start,
                            int* __restrict__ cursor, int N) {
    __shared__ int part[1024];
    int tid = threadIdx.x;
    int CH = (N + 1023) >> 10;
    int base = tid * CH;
    int s = 0;
    for (int i = 0; i < CH; ++i) {
        int idx = base + i;
        if (idx < N) s += deg[idx];
    }
    part[tid] = s;
    __syncthreads();
    for (int off = 1; off < 1024; off <<= 1) {
        int v = (tid >= off) ? part[tid - off] : 0;
        __syncthreads();
        part[tid] += v;
        __syncthreads();
    }
    int run = (tid > 0) ? part[tid - 1] : 0;
    for (int i = 0; i < CH; ++i) {
        int idx = base + i;
        if (idx < N) { row_start[idx] = run; cursor[idx] = run; run += deg[idx]; }
    }
    if (tid == 1023) row_start[N] = part[1023];
}

__global__ void fill_kernel(const int* __restrict__ src, const int* __restrict__ dst,
                            int* __restrict__ cursor, int* __restrict__ csr, int E) {
    int e = blockIdx.x * blockDim.x + threadIdx.x;
    if (e < E) {
        int pos = atomicAdd(&cursor[dst[e]], 1);
        csr[pos] = src[e];
    }
}

// ---------------- Aggregation (gather): h[n] = x[n] + sum_{src->n} x[src] ----------------
template <int D>
__global__ void gather_h_kernel(const float* __restrict__ x, const int* __restrict__ row_start,
                                const int* __restrict__ csr, float* __restrict__ h, int N) {
    int node = blockIdx.x * 4 + (threadIdx.x >> 6);
    if (node >= N) return;
    int lane = threadIdx.x & 63;
    int e0 = row_start[node], e1 = row_start[node + 1];
    if constexpr (D == 256) {
        size_t base = (size_t)node * D + lane * 4;
        float4 acc = *(const float4*)&x[base];
        for (int e = e0; e < e1; ++e) {
            int s = csr[e];
            float4 v = *(const float4*)&x[(size_t)s * D + lane * 4];
            acc.x += v.x; acc.y += v.y; acc.z += v.z; acc.w += v.w;
        }
        *(float4*)&h[base] = acc;
    } else {  // D == 128
        size_t base = (size_t)node * D + lane * 2;
        float2 acc = *(const float2*)&x[base];
        for (int e = e0; e < e1; ++e) {
            int s = csr[e];
            float2 v = *(const float2*)&x[(size_t)s * D + lane * 2];
            acc.x += v.x; acc.y += v.y;
        }
        *(float2*)&h[base] = acc;
    }
}

// out[n] = y[n] + sum y[src] + b   (40 features)
__global__ void gather_out_kernel(const float* __restrict__ y, const int* __restrict__ row_start,
                                  const int* __restrict__ csr, const float* __restrict__ b,
                                  float* __restrict__ out, int N) {
    int node = blockIdx.x * 4 + (threadIdx.x >> 6);
    int lane = threadIdx.x & 63;
    if (node >= N || lane >= 40) return;
    float acc = y[(size_t)node * 40 + lane] + b[lane];
    int e0 = row_start[node], e1 = row_start[node + 1];
    for (int e = e0; e < e1; ++e) acc += y[(size_t)csr[e] * 40 + lane];
    out[(size_t)node * 40 + lane] = acc;
}

// ---------------- fp32 tiled GEMM: C = [relu](A @ W + bias) ----------------
// A: [Mpad, K] (rows padded, loads unguarded), W: [K, N], C: [M, N] (stores guarded)
__global__ __launch_bounds__(256) void gemm_kernel(const float* __restrict__ A,
                                                   const float* __restrict__ W,
                                                   const float* __restrict__ bias,
                                                   float* __restrict__ C,
                                                   int M, int N, int K, int do_relu) {
    __shared__ float As[BK][BM];      // transposed A tile
    __shared__ float Bs[BK][BN];
    int tid = threadIdx.x;
    int tx = tid & 15;   // col group 0..15
    int ty = tid >> 4;   // row group 0..15
    int row0 = blockIdx.x * BM;
    int col0 = blockIdx.y * BN;

    int ar = tid >> 3;          // 0..31
    int ac = (tid & 7) * 4;     // 0..28
    int br = tid >> 4;          // 0..15
    int bc = (tid & 15) * 4;    // 0..60

    float acc[4][4] = {};

    for (int k0 = 0; k0 < K; k0 += BK) {
        float4 a0 = *(const float4*)&A[(size_t)(row0 + ar) * K + k0 + ac];
        float4 a1 = *(const float4*)&A[(size_t)(row0 + ar + 32) * K + k0 + ac];
        float4 b0, b1;
        if (col0 + bc < N) {
            b0 = *(const float4*)&W[(size_t)(k0 + br) * N + col0 + bc];
            b1 = *(const float4*)&W[(size_t)(k0 + br + 16) * N + col0 + bc];
        } else {
            b0 = make_float4(0.f, 0.f, 0.f, 0.f);
            b1 = b0;
        }
        __syncthreads();  // previous tile fully consumed
        As[ac + 0][ar] = a0.x; As[ac + 1][ar] = a0.y; As[ac + 2][ar] = a0.z; As[ac + 3][ar] = a0.w;
        As[ac + 0][ar + 32] = a1.x; As[ac + 1][ar + 32] = a1.y; As[ac + 2][ar + 32] = a1.z; As[ac + 3][ar + 32] = a1.w;
        *(float4*)&Bs[br][bc] = b0;
        *(float4*)&Bs[br + 16][bc] = b1;
        __syncthreads();
        #pragma unroll
        for (int kk = 0; kk < BK; ++kk) {
            float4 av = *(const float4*)&As[kk][ty * 4];
            float4 bv = *(const float4*)&Bs[kk][tx * 4];
            acc[0][0] += av.x * bv.x; acc[0][1] += av.x * bv.y; acc[0][2] += av.x * bv.z; acc[0][3] += av.x * bv.w;
            acc[1][0] += av.y * bv.x; acc[1][1] += av.y * bv.y; acc[1][2] += av.y * bv.z; acc[1][3] += av.y * bv.w;
            acc[2][0] += av.z * bv.x; acc[2][1] += av.z * bv.y; acc[2][2] += av.z * bv.z; acc[2][3] += av.z * bv.w;
            acc[3][0] += av.w * bv.x; acc[3][1] += av.w * bv.y; acc[3][2] += av.w * bv.z; acc[3][3] += av.w * bv.w;
        }
    }

    #pragma unroll
    for (int i = 0; i < 4; ++i) {
        int row = row0 + ty * 4 + i;
        if (row >= M) continue;
        #pragma unroll
        for (int j = 0; j < 4; ++j) {
            int col = col0 + tx * 4 + j;
            if (col >= N) continue;
            float v = acc[i][j] + (bias ? bias[col] : 0.f);
            if (do_relu) v = fmaxf(v, 0.f);
            C[(size_t)row * N + col] = v;
        }
    }
}

// ---------------- launch ----------------
extern "C" void kernel_launch(void* const* d_in, const int* in_sizes, int n_in,
                              void* d_out, int out_size, void* d_ws, size_t ws_size,
                              hipStream_t stream) {
    const float* x  = (const float*)d_in[0];
    const int*   ei = (const int*)d_in[1];
    const float* W1 = (const float*)d_in[2];
    const float* b1 = (const float*)d_in[3];
    const float* W2 = (const float*)d_in[4];
    const float* b2 = (const float*)d_in[5];
    const float* W3 = (const float*)d_in[6];
    const float* b3 = (const float*)d_in[7];
    const float* W4 = (const float*)d_in[8];
    const float* b4 = (const float*)d_in[9];
    float* out = (float*)d_out;

    int N = in_sizes[0] / 128;   // 20000
    int E = in_sizes[1] / 2;     // 640000
    const int* src = ei;
    const int* dst = ei + E;

    char* ws = (char*)d_ws;
    int* row_start = (int*)ws;               // N+1
    int* cursor    = row_start + (N + 1);    // N
    int* deg       = cursor + N;             // N
    int* csr       = deg + N;                // E
    size_t off = ((size_t)(3 * N + 1 + E) * 4 + 255) & ~(size_t)255;
    int Mpad = ((N + BM - 1) / BM) * BM;     // 20032
    float* bufH = (float*)(ws + off); off += (size_t)Mpad * 256 * 4;
    float* bufA = (float*)(ws + off); off += (size_t)Mpad * 256 * 4;
    float* bufB = (float*)(ws + off); off += (size_t)Mpad * 256 * 4;
    float* bufY = (float*)(ws + off); off += (size_t)Mpad * 40 * 4;

    // CSR by destination
    hipMemsetAsync(deg, 0, (size_t)N * 4, stream);
    hist_kernel<<<(E + 255) / 256, 256, 0, stream>>>(dst, deg, E);
    scan_kernel<<<1, 1024, 0, stream>>>(deg, row_start, cursor, N);
    fill_kernel<<<(E + 255) / 256, 256, 0, stream>>>(src, dst, cursor, csr, E);

    int gatherBlocks = (N + 3) / 4;
    dim3 gemmGrid(Mpad / BM, 256 / BN);   // (313, 4)
    dim3 gemmGrid4(Mpad / BM, 1);

    // L1: h1 = x + agg(x) [d=128]; z1 = relu(h1 @ W1 + b1)
    gather_h_kernel<128><<<gatherBlocks, 256, 0, stream>>>(x, row_start, csr, bufH, N);
    gemm_kernel<<<gemmGrid, 256, 0, stream>>>(bufH, W1, b1, bufA, N, 256, 128, 1);
    // L2
    gather_h_kernel<256><<<gatherBlocks, 256, 0, stream>>>(bufA, row_start, csr, bufH, N);
    gemm_kernel<<<gemmGrid, 256, 0, stream>>>(bufH, W2, b2, bufB, N, 256, 256, 1);
    // L3
    gather_h_kernel<256><<<gatherBlocks, 256, 0, stream>>>(bufB, row_start, csr, bufH, N);
    gemm_kernel<<<gemmGrid, 256, 0, stream>>>(bufH, W3, b3, bufA, N, 256, 256, 1);
    // L4: y4 = z3 @ W4 (no bias);  out = y4 + agg(y4) + b4   (agg commutes with linear map)
    gemm_kernel<<<gemmGrid4, 256, 0, stream>>>(bufA, W4, nullptr, bufY, N, 40, 256, 0);
    gather_out_kernel<<<gatherBlocks, 256, 0, stream>>>(bufY, row_start, csr, b4, out, N);
}

// Round 2
// 369.645 us; speedup vs baseline: 1.4744x; 1.4744x over previous
//
#include <hip/hip_runtime.h>

typedef __attribute__((ext_vector_type(8))) short bf16x8;
typedef __attribute__((ext_vector_type(4))) float f32x4;

__device__ __forceinline__ ushort f2bf(float f) {
    union { float f; uint u; } c; c.f = f;
    uint u = c.u;
    u += 0x7fffu + ((u >> 16) & 1u);   // RNE
    return (ushort)(u >> 16);
}
__device__ __forceinline__ float bf2f(uint us) {
    union { uint u; float f; } c; c.u = us << 16;
    return c.f;
}

// ---------------- CSR build ----------------
__global__ void hist_kernel(const int* __restrict__ dst, int* __restrict__ deg, int E) {
    int e = blockIdx.x * blockDim.x + threadIdx.x;
    if (e < E) atomicAdd(&deg[dst[e]], 1);
}

__global__ void scan_kernel(const int* __restrict__ deg, int* __restrict__ row_start,
                            int* __restrict__ cursor, int N) {
    __shared__ int part[1024];
    int tid = threadIdx.x;
    int CH = (N + 1023) >> 10;
    int base = tid * CH;
    int s = 0;
    for (int i = 0; i < CH; ++i) {
        int idx = base + i;
        if (idx < N) s += deg[idx];
    }
    part[tid] = s;
    __syncthreads();
    for (int off = 1; off < 1024; off <<= 1) {
        int v = (tid >= off) ? part[tid - off] : 0;
        __syncthreads();
        part[tid] += v;
        __syncthreads();
    }
    int run = (tid > 0) ? part[tid - 1] : 0;
    for (int i = 0; i < CH; ++i) {
        int idx = base + i;
        if (idx < N) { row_start[idx] = run; cursor[idx] = run; run += deg[idx]; }
    }
    if (tid == 1023) row_start[N] = part[1023];
}

__global__ void fill_kernel(const int* __restrict__ src, const int* __restrict__ dst,
                            int* __restrict__ cursor, ushort* __restrict__ csr, int E) {
    int e = blockIdx.x * blockDim.x + threadIdx.x;
    if (e < E) {
        int pos = atomicAdd(&cursor[dst[e]], 1);
        csr[pos] = (ushort)src[e];
    }
}

// ---------------- conversions ----------------
__global__ void cvt_x_kernel(const float* __restrict__ x, ushort* __restrict__ xb, int n4) {
    int i = blockIdx.x * blockDim.x + threadIdx.x;
    if (i >= n4) return;
    float4 v = *(const float4*)&x[(size_t)i * 4];
    ushort4 o; o.x = f2bf(v.x); o.y = f2bf(v.y); o.z = f2bf(v.z); o.w = f2bf(v.w);
    *(ushort4*)&xb[(size_t)i * 4] = o;
}

// W [K][N] fp32 -> WT [Npad][K] bf16 (zero-fill rows n >= N)
__global__ void cvt_wT_kernel(const float* __restrict__ W, ushort* __restrict__ WT,
                              int K, int N, int Npad) {
    int idx = blockIdx.x * blockDim.x + threadIdx.x;
    if (idx >= K * Npad) return;
    int n = idx % Npad, k = idx / Npad;
    float v = (n < N) ? W[(size_t)k * N + n] : 0.f;
    WT[(size_t)n * K + k] = f2bf(v);
}

// ---------------- XCD-chunked gather: h[n] = x[n] + sum_{src->n} x[src] (bf16) ----------------
// 4 feature chunks; chunk = blockIdx.x & 3 so each XCD's L2 holds only its ~2.5MB slice.
template <int D>
__global__ __launch_bounds__(256) void gather_chunk(
        const ushort* __restrict__ xb, const int* __restrict__ row_start,
        const ushort* __restrict__ csr, ushort* __restrict__ h, int N) {
    constexpr int CF = D / 4;        // feats per chunk: 32 (D=128) or 64 (D=256)
    constexpr int PL = CF / 16;      // feats per lane: 2 or 4
    int chunk = blockIdx.x & 3;
    int node = (blockIdx.x >> 2) * 16 + (threadIdx.x >> 4);
    if (node >= N) return;
    int l = threadIdx.x & 15;
    size_t fo = (size_t)chunk * CF + (size_t)l * PL;
    int e0 = row_start[node], e1 = row_start[node + 1];
    if constexpr (PL == 2) {
        uint sv = *(const uint*)&xb[(size_t)node * D + fo];
        float a0 = bf2f(sv & 0xffffu), a1 = bf2f(sv >> 16);
        for (int e = e0; e < e1; ++e) {
            uint s = csr[e];
            uint v = *(const uint*)&xb[(size_t)s * D + fo];
            a0 += bf2f(v & 0xffffu); a1 += bf2f(v >> 16);
        }
        *(uint*)&h[(size_t)node * D + fo] = (uint)f2bf(a0) | ((uint)f2bf(a1) << 16);
    } else {
        uint2 sv = *(const uint2*)&xb[(size_t)node * D + fo];
        float a0 = bf2f(sv.x & 0xffffu), a1 = bf2f(sv.x >> 16);
        float a2 = bf2f(sv.y & 0xffffu), a3 = bf2f(sv.y >> 16);
        for (int e = e0; e < e1; ++e) {
            uint s = csr[e];
            uint2 v = *(const uint2*)&xb[(size_t)s * D + fo];
            a0 += bf2f(v.x & 0xffffu); a1 += bf2f(v.x >> 16);
            a2 += bf2f(v.y & 0xffffu); a3 += bf2f(v.y >> 16);
        }
        uint2 o;
        o.x = (uint)f2bf(a0) | ((uint)f2bf(a1) << 16);
        o.y = (uint)f2bf(a2) | ((uint)f2bf(a3) << 16);
        *(uint2*)&h[(size_t)node * D + fo] = o;
    }
}

// out[n] = y[n] + sum y[src] + b   (40 fp32 features)
__global__ void gather_out_kernel(const float* __restrict__ y, const int* __restrict__ row_start,
                                  const ushort* __restrict__ csr, const float* __restrict__ b,
                                  float* __restrict__ out, int N) {
    int node = blockIdx.x * 4 + (threadIdx.x >> 6);
    int lane = threadIdx.x & 63;
    if (node >= N || lane >= 40) return;
    float acc = y[(size_t)node * 40 + lane] + b[lane];
    int e0 = row_start[node], e1 = row_start[node + 1];
    for (int e = e0; e < e1; ++e) acc += y[(size_t)csr[e] * 40 + lane];
    out[(size_t)node * 40 + lane] = acc;
}

// ---------------- MFMA bf16 GEMM: C = [relu](A @ B + bias) ----------------
// A: [Mpad][K] bf16 row-major.  BT: [Npad][K] bf16 (pre-transposed W).  C: [M][Ncols].
#define GBM 128
#define GBN 128
#define GBK 32
#define LDT 40   // padded LDS row stride (shorts): 80B -> only 2-way bank aliasing (free)

template <bool OUTF32, bool RELU>
__global__ __launch_bounds__(256) void mfma_gemm(
        const ushort* __restrict__ A, const ushort* __restrict__ BT,
        const float* __restrict__ bias, void* __restrict__ Cout,
        int M, int Ncols, int K) {
    __shared__ __align__(16) ushort As[GBM * LDT];
    __shared__ __align__(16) ushort Bs[GBN * LDT];
    int tid = threadIdx.x;
    int lane = tid & 63;
    int wave = tid >> 6;
    int row0 = blockIdx.x * GBM;
    int col0 = blockIdx.y * GBN;
    int wr = (wave >> 1) * 64;   // wave's row offset in tile
    int wc = (wave & 1) * 64;    // wave's col offset in tile
    int sr = tid >> 2;           // staging row 0..63
    int sc = (tid & 3) * 8;      // staging col chunk (8 shorts = 16B)
    int rr = lane & 15;
    int kq = (lane >> 4) * 8;    // A/B frag k-offset: lane holds elems k = kq..kq+7
    f32x4 acc[4][4] = {};

    for (int k0 = 0; k0 < K; k0 += GBK) {
        int4 a0 = *(const int4*)&A[(size_t)(row0 + sr) * K + k0 + sc];
        int4 a1 = *(const int4*)&A[(size_t)(row0 + sr + 64) * K + k0 + sc];
        int4 b0 = *(const int4*)&BT[(size_t)(col0 + sr) * K + k0 + sc];
        int4 b1 = *(const int4*)&BT[(size_t)(col0 + sr + 64) * K + k0 + sc];
        __syncthreads();   // previous tile fully consumed
        *(int4*)&As[sr * LDT + sc] = a0;
        *(int4*)&As[(sr + 64) * LDT + sc] = a1;
        *(int4*)&Bs[sr * LDT + sc] = b0;
        *(int4*)&Bs[(sr + 64) * LDT + sc] = b1;
        __syncthreads();
        bf16x8 af[4], bf[4];
        #pragma unroll
        for (int i = 0; i < 4; ++i)
            af[i] = *(const bf16x8*)&As[(wr + i * 16 + rr) * LDT + kq];
        #pragma unroll
        for (int j = 0; j < 4; ++j)
            bf[j] = *(const bf16x8*)&Bs[(wc + j * 16 + rr) * LDT + kq];
        #pragma unroll
        for (int i = 0; i < 4; ++i)
            #pragma unroll
            for (int j = 0; j < 4; ++j)
                acc[i][j] = __builtin_amdgcn_mfma_f32_16x16x32_bf16(af[i], bf[j], acc[i][j], 0, 0, 0);
    }

    // epilogue: D frag layout col = lane&15, row = (lane>>4)*4 + r  [m89-verified]
    int rq = (lane >> 4) * 4;
    #pragma unroll
    for (int j = 0; j < 4; ++j) {
        int col = col0 + wc + j * 16 + rr;
        if (col >= Ncols) continue;
        float bv = bias ? bias[col] : 0.f;
        #pragma unroll
        for (int i = 0; i < 4; ++i) {
            #pragma unroll
            for (int r = 0; r < 4; ++r) {
                int row = row0 + wr + i * 16 + rq + r;
                if (row >= M) continue;
                float v = acc[i][j][r] + bv;
                if (RELU) v = fmaxf(v, 0.f);
                if (OUTF32) ((float*)Cout)[(size_t)row * Ncols + col] = v;
                else        ((ushort*)Cout)[(size_t)row * Ncols + col] = f2bf(v);
            }
        }
    }
}

// ---------------- launch ----------------
static inline size_t al256(size_t x) { return (x + 255) & ~(size_t)255; }

extern "C" void kernel_launch(void* const* d_in, const int* in_sizes, int n_in,
                              void* d_out, int out_size, void* d_ws, size_t ws_size,
                              hipStream_t stream) {
    const float* x  = (const float*)d_in[0];
    const int*   ei = (const int*)d_in[1];
    const float* W1 = (const float*)d_in[2];
    const float* b1 = (const float*)d_in[3];
    const float* W2 = (const float*)d_in[4];
    const float* b2 = (const float*)d_in[5];
    const float* W3 = (const float*)d_in[6];
    const float* b3 = (const float*)d_in[7];
    const float* W4 = (const float*)d_in[8];
    const float* b4 = (const float*)d_in[9];
    float* out = (float*)d_out;

    int N = in_sizes[0] / 128;   // 20000
    int E = in_sizes[1] / 2;     // 640000
    const int* src = ei;
    const int* dst = ei + E;
    int Mpad = ((N + GBM - 1) / GBM) * GBM;

    char* ws = (char*)d_ws;
    int* row_start = (int*)ws;                      // N+1
    int* cursor    = row_start + (N + 1);           // N
    int* deg       = cursor + N;                    // N
    ushort* csr    = (ushort*)(deg + N);            // E (u16 node ids, N < 65536)
    size_t off = al256((size_t)(3 * N + 1) * 4 + (size_t)E * 2);
    ushort* xb   = (ushort*)(ws + off); off += al256((size_t)N * 128 * 2);
    ushort* bufH = (ushort*)(ws + off); off += al256((size_t)Mpad * 256 * 2);
    ushort* bufA = (ushort*)(ws + off); off += al256((size_t)Mpad * 256 * 2);
    ushort* bufB = (ushort*)(ws + off); off += al256((size_t)Mpad * 256 * 2);
    float*  bufY = (float*)(ws + off);  off += al256((size_t)Mpad * 40 * 4);
    ushort* W1T  = (ushort*)(ws + off); off += al256((size_t)256 * 128 * 2);
    ushort* W2T  = (ushort*)(ws + off); off += al256((size_t)256 * 256 * 2);
    ushort* W3T  = (ushort*)(ws + off); off += al256((size_t)256 * 256 * 2);
    ushort* W4T  = (ushort*)(ws + off); off += al256((size_t)128 * 256 * 2);

    // CSR by destination
    hipMemsetAsync(deg, 0, (size_t)N * 4, stream);
    hist_kernel<<<(E + 255) / 256, 256, 0, stream>>>(dst, deg, E);
    scan_kernel<<<1, 1024, 0, stream>>>(deg, row_start, cursor, N);
    fill_kernel<<<(E + 255) / 256, 256, 0, stream>>>(src, dst, cursor, csr, E);

    // conversions
    cvt_x_kernel<<<(N * 128 / 4 + 255) / 256, 256, 0, stream>>>(x, xb, N * 128 / 4);
    cvt_wT_kernel<<<(128 * 256 + 255) / 256, 256, 0, stream>>>(W1, W1T, 128, 256, 256);
    cvt_wT_kernel<<<(256 * 256 + 255) / 256, 256, 0, stream>>>(W2, W2T, 256, 256, 256);
    cvt_wT_kernel<<<(256 * 256 + 255) / 256, 256, 0, stream>>>(W3, W3T, 256, 256, 256);
    cvt_wT_kernel<<<(256 * 128 + 255) / 256, 256, 0, stream>>>(W4, W4T, 256, 40, 128);

    int gcBlocks = ((N + 15) / 16) * 4;
    dim3 gemmGrid(Mpad / GBM, 2);
    dim3 gemmGrid4(Mpad / GBM, 1);

    // L1
    gather_chunk<128><<<gcBlocks, 256, 0, stream>>>(xb, row_start, csr, bufH, N);
    mfma_gemm<false, true><<<gemmGrid, 256, 0, stream>>>(bufH, W1T, b1, bufA, N, 256, 128);
    // L2
    gather_chunk<256><<<gcBlocks, 256, 0, stream>>>(bufA, row_start, csr, bufH, N);
    mfma_gemm<false, true><<<gemmGrid, 256, 0, stream>>>(bufH, W2T, b2, bufB, N, 256, 256);
    // L3
    gather_chunk<256><<<gcBlocks, 256, 0, stream>>>(bufB, row_start, csr, bufH, N);
    mfma_gemm<false, true><<<gemmGrid, 256, 0, stream>>>(bufH, W3T, b3, bufA, N, 256, 256);
    // L4: y4 = z3 @ W4 ; out = y4 + agg(y4) + b4  (agg commutes with linear map)
    mfma_gemm<true, false><<<gemmGrid4, 256, 0, stream>>>(bufA, W4T, nullptr, bufY, N, 40, 256);
    gather_out_kernel<<<(N + 3) / 4, 256, 0, stream>>>(bufY, row_start, csr, b4, out, N);
}

// Round 3
// 300.163 us; speedup vs baseline: 1.8157x; 1.2315x over previous
//
#include <hip/hip_runtime.h>

typedef __attribute__((ext_vector_type(8))) short bf16x8;
typedef __attribute__((ext_vector_type(4))) float f32x4;

__device__ __forceinline__ ushort f2bf(float f) {
    union { float f; uint u; } c; c.f = f;
    uint u = c.u;
    u += 0x7fffu + ((u >> 16) & 1u);   // RNE
    return (ushort)(u >> 16);
}
__device__ __forceinline__ float bf_lo(uint u) { union { uint u; float f; } c; c.u = u << 16; return c.f; }
__device__ __forceinline__ float bf_hi(uint u) { union { uint u; float f; } c; c.u = u & 0xffff0000u; return c.f; }

// ---------------- CSR build ----------------
__global__ void hist_kernel(const int* __restrict__ dst, int* __restrict__ deg, int E) {
    int e = blockIdx.x * blockDim.x + threadIdx.x;
    if (e < E) atomicAdd(&deg[dst[e]], 1);
}

__global__ void scan_kernel(const int* __restrict__ deg, int* __restrict__ row_start,
                            int* __restrict__ cursor, int N) {
    __shared__ int part[1024];
    int tid = threadIdx.x;
    int CH = (N + 1023) >> 10;
    int base = tid * CH;
    int s = 0;
    for (int i = 0; i < CH; ++i) {
        int idx = base + i;
        if (idx < N) s += deg[idx];
    }
    part[tid] = s;
    __syncthreads();
    for (int off = 1; off < 1024; off <<= 1) {
        int v = (tid >= off) ? part[tid - off] : 0;
        __syncthreads();
        part[tid] += v;
        __syncthreads();
    }
    int run = (tid > 0) ? part[tid - 1] : 0;
    for (int i = 0; i < CH; ++i) {
        int idx = base + i;
        if (idx < N) { row_start[idx] = run; cursor[idx] = run; run += deg[idx]; }
    }
    if (tid == 1023) row_start[N] = part[1023];
}

__global__ void fill_kernel(const int* __restrict__ src, const int* __restrict__ dst,
                            int* __restrict__ cursor, ushort* __restrict__ csr, int E) {
    int e = blockIdx.x * blockDim.x + threadIdx.x;
    if (e < E) {
        int pos = atomicAdd(&cursor[dst[e]], 1);
        csr[pos] = (ushort)src[e];
    }
}

// ---------------- merged conversions: x -> bf16, all W -> bf16 transposed ----------------
// seg0: idx < NX4          : x fp32 -> xb bf16, 4 elems/thread
// seg1..4: weight transposes  WT[Npad][K] <- W[K][N]
__global__ void cvt_all(const float* __restrict__ x, ushort* __restrict__ xb, int n4,
                        const float* __restrict__ W1, ushort* __restrict__ W1T,
                        const float* __restrict__ W2, ushort* __restrict__ W2T,
                        const float* __restrict__ W3, ushort* __restrict__ W3T,
                        const float* __restrict__ W4, ushort* __restrict__ W4T) {
    int idx = blockIdx.x * blockDim.x + threadIdx.x;
    if (idx < n4) {
        float4 v = *(const float4*)&x[(size_t)idx * 4];
        ushort4 o; o.x = f2bf(v.x); o.y = f2bf(v.y); o.z = f2bf(v.z); o.w = f2bf(v.w);
        *(ushort4*)&xb[(size_t)idx * 4] = o;
        return;
    }
    int i = idx - n4;
    if (i < 32768) {                       // W1: K=128 N=256 Npad=256
        int n = i & 255, k = i >> 8;
        W1T[n * 128 + k] = f2bf(W1[k * 256 + n]);
    } else if (i < 32768 + 65536) {        // W2
        int j = i - 32768; int n = j & 255, k = j >> 8;
        W2T[n * 256 + k] = f2bf(W2[k * 256 + n]);
    } else if (i < 32768 + 131072) {       // W3
        int j = i - 98304; int n = j & 255, k = j >> 8;
        W3T[n * 256 + k] = f2bf(W3[k * 256 + n]);
    } else if (i < 32768 + 131072 + 32768) { // W4: K=256 N=40 Npad=128
        int j = i - 163840; int n = j & 127, k = j >> 7;
        W4T[n * 256 + k] = f2bf(n < 40 ? W4[k * 40 + n] : 0.f);
    }
}

// ---------------- XCD-chunked gather: h[n] = x[n] + sum_{src->n} x[src] (bf16) ----------------
// 4 feature chunks; chunk = blockIdx.x & 3 so each XCD's L2 holds only its slice.
// Edge loop unrolled x4 with independent accumulator sets to hide L2 latency.
template <int D>
__global__ __launch_bounds__(256) void gather_chunk(
        const ushort* __restrict__ xb, const int* __restrict__ row_start,
        const ushort* __restrict__ csr, ushort* __restrict__ h, int N) {
    constexpr int CF = D / 4;            // feats per chunk: 32 (D=128) or 64 (D=256)
    constexpr int PL = CF / 16;          // feats per lane: 2 or 4
    constexpr int RS = (D == 256) ? 9 : 8;  // log2(row bytes)
    int chunk = blockIdx.x & 3;
    int node = (blockIdx.x >> 2) * 16 + (threadIdx.x >> 4);
    if (node >= N) return;
    int l = threadIdx.x & 15;
    uint fo2 = (uint)(chunk * CF + l * PL) * 2;   // byte offset within row
    const char* xc = (const char*)xb;
    char* hc = (char*)h;
    int e0 = row_start[node], e1 = row_start[node + 1];
    uint selfoff = ((uint)node << RS) + fo2;

    if constexpr (PL == 4) {
        uint2 sv = *(const uint2*)(xc + selfoff);
        float a0 = bf_lo(sv.x), a1 = bf_hi(sv.x), a2 = bf_lo(sv.y), a3 = bf_hi(sv.y);
        float b0 = 0, b1 = 0, b2 = 0, b3 = 0;
        float c0 = 0, c1 = 0, c2 = 0, c3 = 0;
        float d0 = 0, d1 = 0, d2 = 0, d3 = 0;
        int e = e0;
        for (; e + 4 <= e1; e += 4) {
            uint s0 = csr[e], s1 = csr[e + 1], s2 = csr[e + 2], s3 = csr[e + 3];
            uint2 v0 = *(const uint2*)(xc + (s0 << RS) + fo2);
            uint2 v1 = *(const uint2*)(xc + (s1 << RS) + fo2);
            uint2 v2 = *(const uint2*)(xc + (s2 << RS) + fo2);
            uint2 v3 = *(const uint2*)(xc + (s3 << RS) + fo2);
            a0 += bf_lo(v0.x); a1 += bf_hi(v0.x); a2 += bf_lo(v0.y); a3 += bf_hi(v0.y);
            b0 += bf_lo(v1.x); b1 += bf_hi(v1.x); b2 += bf_lo(v1.y); b3 += bf_hi(v1.y);
            c0 += bf_lo(v2.x); c1 += bf_hi(v2.x); c2 += bf_lo(v2.y); c3 += bf_hi(v2.y);
            d0 += bf_lo(v3.x); d1 += bf_hi(v3.x); d2 += bf_lo(v3.y); d3 += bf_hi(v3.y);
        }
        for (; e < e1; ++e) {
            uint s = csr[e];
            uint2 v = *(const uint2*)(xc + (s << RS) + fo2);
            a0 += bf_lo(v.x); a1 += bf_hi(v.x); a2 += bf_lo(v.y); a3 += bf_hi(v.y);
        }
        a0 += (b0 + c0) + d0; a1 += (b1 + c1) + d1;
        a2 += (b2 + c2) + d2; a3 += (b3 + c3) + d3;
        uint2 o;
        o.x = (uint)f2bf(a0) | ((uint)f2bf(a1) << 16);
        o.y = (uint)f2bf(a2) | ((uint)f2bf(a3) << 16);
        *(uint2*)(hc + selfoff) = o;
    } else {
        uint sv = *(const uint*)(xc + selfoff);
        float a0 = bf_lo(sv), a1 = bf_hi(sv);
        float b0 = 0, b1 = 0, c0 = 0, c1 = 0, d0 = 0, d1 = 0;
        int e = e0;
        for (; e + 4 <= e1; e += 4) {
            uint s0 = csr[e], s1 = csr[e + 1], s2 = csr[e + 2], s3 = csr[e + 3];
            uint v0 = *(const uint*)(xc + (s0 << RS) + fo2);
            uint v1 = *(const uint*)(xc + (s1 << RS) + fo2);
            uint v2 = *(const uint*)(xc + (s2 << RS) + fo2);
            uint v3 = *(const uint*)(xc + (s3 << RS) + fo2);
            a0 += bf_lo(v0); a1 += bf_hi(v0);
            b0 += bf_lo(v1); b1 += bf_hi(v1);
            c0 += bf_lo(v2); c1 += bf_hi(v2);
            d0 += bf_lo(v3); d1 += bf_hi(v3);
        }
        for (; e < e1; ++e) {
            uint s = csr[e];
            uint v = *(const uint*)(xc + (s << RS) + fo2);
            a0 += bf_lo(v); a1 += bf_hi(v);
        }
        a0 += (b0 + c0) + d0; a1 += (b1 + c1) + d1;
        *(uint*)(hc + selfoff) = (uint)f2bf(a0) | ((uint)f2bf(a1) << 16);
    }
}

// out[n] = y[n] + sum y[src] + b   (40 fp32 features), unrolled x4
__global__ void gather_out_kernel(const float* __restrict__ y, const int* __restrict__ row_start,
                                  const ushort* __restrict__ csr, const float* __restrict__ b,
                                  float* __restrict__ out, int N) {
    int node = blockIdx.x * 4 + (threadIdx.x >> 6);
    int lane = threadIdx.x & 63;
    if (node >= N || lane >= 40) return;
    const char* yc = (const char*)y;
    uint lb = (uint)lane * 4;
    float a = y[(size_t)node * 40 + lane] + b[lane];
    float bb = 0, cc = 0, dd = 0;
    int e0 = row_start[node], e1 = row_start[node + 1];
    int e = e0;
    for (; e + 4 <= e1; e += 4) {
        uint s0 = csr[e], s1 = csr[e + 1], s2 = csr[e + 2], s3 = csr[e + 3];
        a  += *(const float*)(yc + s0 * 160u + lb);
        bb += *(const float*)(yc + s1 * 160u + lb);
        cc += *(const float*)(yc + s2 * 160u + lb);
        dd += *(const float*)(yc + s3 * 160u + lb);
    }
    for (; e < e1; ++e) a += *(const float*)(yc + (uint)csr[e] * 160u + lb);
    out[(size_t)node * 40 + lane] = a + (bb + cc) + dd;
}

// ---------------- MFMA bf16 GEMM: C = [relu](A @ B + bias) ----------------
#define GBM 128
#define GBN 128
#define GBK 32
#define LDT 40   // padded LDS row stride (shorts): 80B -> only 2-way bank aliasing (free)

template <bool OUTF32, bool RELU>
__global__ __launch_bounds__(256) void mfma_gemm(
        const ushort* __restrict__ A, const ushort* __restrict__ BT,
        const float* __restrict__ bias, void* __restrict__ Cout,
        int M, int Ncols, int K) {
    __shared__ __align__(16) ushort As[GBM * LDT];
    __shared__ __align__(16) ushort Bs[GBN * LDT];
    int tid = threadIdx.x;
    int lane = tid & 63;
    int wave = tid >> 6;
    int row0 = blockIdx.x * GBM;
    int col0 = blockIdx.y * GBN;
    int wr = (wave >> 1) * 64;
    int wc = (wave & 1) * 64;
    int sr = tid >> 2;
    int sc = (tid & 3) * 8;
    int rr = lane & 15;
    int kq = (lane >> 4) * 8;
    f32x4 acc[4][4] = {};

    for (int k0 = 0; k0 < K; k0 += GBK) {
        int4 a0 = *(const int4*)&A[(size_t)(row0 + sr) * K + k0 + sc];
        int4 a1 = *(const int4*)&A[(size_t)(row0 + sr + 64) * K + k0 + sc];
        int4 b0 = *(const int4*)&BT[(size_t)(col0 + sr) * K + k0 + sc];
        int4 b1 = *(const int4*)&BT[(size_t)(col0 + sr + 64) * K + k0 + sc];
        __syncthreads();
        *(int4*)&As[sr * LDT + sc] = a0;
        *(int4*)&As[(sr + 64) * LDT + sc] = a1;
        *(int4*)&Bs[sr * LDT + sc] = b0;
        *(int4*)&Bs[(sr + 64) * LDT + sc] = b1;
        __syncthreads();
        bf16x8 af[4], bfr[4];
        #pragma unroll
        for (int i = 0; i < 4; ++i)
            af[i] = *(const bf16x8*)&As[(wr + i * 16 + rr) * LDT + kq];
        #pragma unroll
        for (int j = 0; j < 4; ++j)
            bfr[j] = *(const bf16x8*)&Bs[(wc + j * 16 + rr) * LDT + kq];
        #pragma unroll
        for (int i = 0; i < 4; ++i)
            #pragma unroll
            for (int j = 0; j < 4; ++j)
                acc[i][j] = __builtin_amdgcn_mfma_f32_16x16x32_bf16(af[i], bfr[j], acc[i][j], 0, 0, 0);
    }

    int rq = (lane >> 4) * 4;
    #pragma unroll
    for (int j = 0; j < 4; ++j) {
        int col = col0 + wc + j * 16 + rr;
        if (col >= Ncols) continue;
        float bv = bias ? bias[col] : 0.f;
        #pragma unroll
        for (int i = 0; i < 4; ++i) {
            #pragma unroll
            for (int r = 0; r < 4; ++r) {
                int row = row0 + wr + i * 16 + rq + r;
                if (row >= M) continue;
                float v = acc[i][j][r] + bv;
                if (RELU) v = fmaxf(v, 0.f);
                if (OUTF32) ((float*)Cout)[(size_t)row * Ncols + col] = v;
                else        ((ushort*)Cout)[(size_t)row * Ncols + col] = f2bf(v);
            }
        }
    }
}

// ---------------- launch ----------------
static inline size_t al256(size_t x) { return (x + 255) & ~(size_t)255; }

extern "C" void kernel_launch(void* const* d_in, const int* in_sizes, int n_in,
                              void* d_out, int out_size, void* d_ws, size_t ws_size,
                              hipStream_t stream) {
    const float* x  = (const float*)d_in[0];
    const int*   ei = (const int*)d_in[1];
    const float* W1 = (const float*)d_in[2];
    const float* b1 = (const float*)d_in[3];
    const float* W2 = (const float*)d_in[4];
    const float* b2 = (const float*)d_in[5];
    const float* W3 = (const float*)d_in[6];
    const float* b3 = (const float*)d_in[7];
    const float* W4 = (const float*)d_in[8];
    const float* b4 = (const float*)d_in[9];
    float* out = (float*)d_out;

    int N = in_sizes[0] / 128;   // 20000
    int E = in_sizes[1] / 2;     // 640000
    const int* src = ei;
    const int* dst = ei + E;
    int Mpad = ((N + GBM - 1) / GBM) * GBM;

    char* ws = (char*)d_ws;
    int* row_start = (int*)ws;                      // N+1
    int* cursor    = row_start + (N + 1);           // N
    int* deg       = cursor + N;                    // N
    ushort* csr    = (ushort*)(deg + N);            // E (u16 node ids)
    size_t off = al256((size_t)(3 * N + 1) * 4 + (size_t)E * 2);
    ushort* xb   = (ushort*)(ws + off); off += al256((size_t)N * 128 * 2);
    ushort* bufH = (ushort*)(ws + off); off += al256((size_t)Mpad * 256 * 2);
    ushort* bufA = (ushort*)(ws + off); off += al256((size_t)Mpad * 256 * 2);
    ushort* bufB = (ushort*)(ws + off); off += al256((size_t)Mpad * 256 * 2);
    float*  bufY = (float*)(ws + off);  off += al256((size_t)Mpad * 40 * 4);
    ushort* W1T  = (ushort*)(ws + off); off += al256((size_t)256 * 128 * 2);
    ushort* W2T  = (ushort*)(ws + off); off += al256((size_t)256 * 256 * 2);
    ushort* W3T  = (ushort*)(ws + off); off += al256((size_t)256 * 256 * 2);
    ushort* W4T  = (ushort*)(ws + off); off += al256((size_t)128 * 256 * 2);

    // CSR by destination
    hipMemsetAsync(deg, 0, (size_t)N * 4, stream);
    hist_kernel<<<(E + 255) / 256, 256, 0, stream>>>(dst, deg, E);
    scan_kernel<<<1, 1024, 0, stream>>>(deg, row_start, cursor, N);
    fill_kernel<<<(E + 255) / 256, 256, 0, stream>>>(src, dst, cursor, csr, E);

    // merged conversions
    int n4 = N * 128 / 4;
    int cvtTotal = n4 + 32768 + 65536 + 65536 + 32768;
    cvt_all<<<(cvtTotal + 255) / 256, 256, 0, stream>>>(x, xb, n4, W1, W1T, W2, W2T, W3, W3T, W4, W4T);

    int gcBlocks = ((N + 15) / 16) * 4;
    dim3 gemmGrid(Mpad / GBM, 2);
    dim3 gemmGrid4(Mpad / GBM, 1);

    // L1
    gather_chunk<128><<<gcBlocks, 256, 0, stream>>>(xb, row_start, csr, bufH, N);
    mfma_gemm<false, true><<<gemmGrid, 256, 0, stream>>>(bufH, W1T, b1, bufA, N, 256, 128);
    // L2
    gather_chunk<256><<<gcBlocks, 256, 0, stream>>>(bufA, row_start, csr, bufH, N);
    mfma_gemm<false, true><<<gemmGrid, 256, 0, stream>>>(bufH, W2T, b2, bufB, N, 256, 256);
    // L3
    gather_chunk<256><<<gcBlocks, 256, 0, stream>>>(bufB, row_start, csr, bufH, N);
    mfma_gemm<false, true><<<gemmGrid, 256, 0, stream>>>(bufH, W3T, b3, bufA, N, 256, 256);
    // L4: y4 = z3 @ W4 ; out = y4 + agg(y4) + b4  (agg commutes with linear map)
    mfma_gemm<true, false><<<gemmGrid4, 256, 0, stream>>>(bufA, W4T, nullptr, bufY, N, 40, 256);
    gather_out_kernel<<<(N + 3) / 4, 256, 0, stream>>>(bufY, row_start, csr, b4, out, N);
}